// Round 1
// baseline (463.891 us; speedup 1.0000x reference)
//
#include <hip/hip_runtime.h>
#include <cstdint>

#define N_TOK 4096
#define DIM   1024
#define NEXP  8
#define FDIM  2048

typedef _Float16 f16_t;
typedef _Float16 f16x8 __attribute__((ext_vector_type(8)));
typedef float    f32x4 __attribute__((ext_vector_type(4)));

__device__ inline unsigned packh(float a, float b) {
    union { f16_t h[2]; unsigned u; } p;
    p.h[0] = (f16_t)a; p.h[1] = (f16_t)b;
    return p.u;
}

// async global->LDS, 16B per lane; LDS dest must be base + lane*16 (it is, by construction)
__device__ inline void gl2lds16(const void* g, void* l) {
    __builtin_amdgcn_global_load_lds(
        (const __attribute__((address_space(1))) unsigned*)g,
        (__attribute__((address_space(3))) unsigned*)l, 16, 0, 0);
}

template<int N>
__device__ inline void vmw() {
    asm volatile("s_waitcnt vmcnt(%0)" :: "i"(N) : "memory");
}

// ---------------- Router: fp32 logits -> softmax -> top2 -> two-level scatter ----------------
__global__ __launch_bounds__(256) void router_kernel(
    const float* __restrict__ x, const float* __restrict__ wr,
    float* __restrict__ topw, int* __restrict__ counts, int* __restrict__ bucket)
{
    __shared__ float r[NEXP][DIM];   // router transposed, 32 KB
    __shared__ int sIdx[32];         // per-block top2 expert ids, 2 per token
    int tid = threadIdx.x;
    for (int i = tid; i < DIM * NEXP / 4; i += 256) {
        float4 v = ((const float4*)wr)[i];
        int base = i * 4;                    // flat = d*8 + e
        r[(base + 0) & 7][(base + 0) >> 3] = v.x;
        r[(base + 1) & 7][(base + 1) >> 3] = v.y;
        r[(base + 2) & 7][(base + 2) >> 3] = v.z;
        r[(base + 3) & 7][(base + 3) >> 3] = v.w;
    }
    __syncthreads();
    int wave = tid >> 6, lane = tid & 63;
    int t0 = blockIdx.x * 16 + wave * 4;
    for (int tt = 0; tt < 4; ++tt) {
        int t = t0 + tt;
        float acc[NEXP];
#pragma unroll
        for (int e = 0; e < NEXP; e++) acc[e] = 0.f;
        const float* xr = x + (size_t)t * DIM;
#pragma unroll
        for (int k = 0; k < DIM / 64; k++) {
            int d = lane + k * 64;
            float xv = xr[d];
#pragma unroll
            for (int e = 0; e < NEXP; e++) acc[e] += xv * r[e][d];
        }
#pragma unroll
        for (int e = 0; e < NEXP; e++) {
#pragma unroll
            for (int off = 32; off > 0; off >>= 1)
                acc[e] += __shfl_xor(acc[e], off, 64);
        }
        if (lane == 0) {
            float mx = acc[0];
#pragma unroll
            for (int e = 1; e < NEXP; e++) mx = fmaxf(mx, acc[e]);
            float p[NEXP]; float s = 0.f;
#pragma unroll
            for (int e = 0; e < NEXP; e++) { p[e] = expf(acc[e] - mx); s += p[e]; }
            float inv = 1.f / s;
#pragma unroll
            for (int e = 0; e < NEXP; e++) p[e] *= inv;
            int i1 = 0; float p1 = p[0];
#pragma unroll
            for (int e = 1; e < NEXP; e++) if (p[e] > p1) { p1 = p[e]; i1 = e; }
            int i2 = -1; float p2 = -1.f;
#pragma unroll
            for (int e = 0; e < NEXP; e++) if (e != i1 && p[e] > p2) { p2 = p[e]; i2 = e; }
            float e2 = expf(p2 - p1);          // softmax over top-2 probs
            float w1 = 1.f / (1.f + e2);
            topw[t * 2 + 0] = w1;
            topw[t * 2 + 1] = e2 * w1;
            int j = (wave * 4 + tt) * 2;
            sIdx[j + 0] = i1;
            sIdx[j + 1] = i2;
        }
    }
    __syncthreads();
    if (tid < NEXP) {
        int cnt = 0;
#pragma unroll
        for (int j = 0; j < 32; j++) cnt += (sIdx[j] == tid) ? 1 : 0;
        if (cnt > 0) {
            int pos = atomicAdd(&counts[tid * 32], cnt);
#pragma unroll
            for (int j = 0; j < 32; j++)
                if (sIdx[j] == tid)
                    bucket[tid * N_TOK + pos++] = (blockIdx.x * 16 + (j >> 1)) * 2 + (j & 1);
        }
    }
}

// ---------------- x: fp32 -> f16 ----------------
__global__ __launch_bounds__(256) void xcast_kernel(const float* __restrict__ x, f16_t* __restrict__ xf)
{
    int i = blockIdx.x * 256 + threadIdx.x;   // 8 elements per thread
    float4 a = ((const float4*)x)[2 * i];
    float4 b = ((const float4*)x)[2 * i + 1];
    union { f16_t h[8]; uint4 u; } p;
    p.h[0] = (f16_t)a.x; p.h[1] = (f16_t)a.y; p.h[2] = (f16_t)a.z; p.h[3] = (f16_t)a.w;
    p.h[4] = (f16_t)b.x; p.h[5] = (f16_t)b.y; p.h[6] = (f16_t)b.z; p.h[7] = (f16_t)b.w;
    ((uint4*)xf)[i] = p.u;
}

// ---------------- Weight transpose+convert: in [R][C] fp32 -> out [C][R] f16 ----------------
__global__ __launch_bounds__(256) void transpose_cvt(
    const float* __restrict__ inA, const float* __restrict__ inB,
    f16_t* __restrict__ outA, f16_t* __restrict__ outB,
    int R, int C, int tiles_r, int nA)
{
    __shared__ unsigned sP[64][68];
    int m = blockIdx.y;
    const float* in; f16_t* out;
    if (m < nA) { in = inA + (size_t)m * DIM * FDIM; out = outA + (size_t)m * DIM * FDIM; }
    else        { in = inB + (size_t)(m - nA) * DIM * FDIM; out = outB + (size_t)(m - nA) * DIM * FDIM; }
    int tix = blockIdx.x;
    int rb = (tix % tiles_r) * 128;
    int cb = (tix / tiles_r) * 64;
    int t = threadIdx.x;
    int dp = t >> 2;
    int fc = (t & 3) * 16;
    const float* r0 = in + (size_t)(rb + 2 * dp) * C + cb + fc;
    const float* r1 = r0 + C;
#pragma unroll
    for (int j = 0; j < 16; j += 4) {
        float4 a = *(const float4*)(r0 + j);
        float4 b = *(const float4*)(r1 + j);
        sP[fc + j + 0][dp] = packh(a.x, b.x);
        sP[fc + j + 1][dp] = packh(a.y, b.y);
        sP[fc + j + 2][dp] = packh(a.z, b.z);
        sP[fc + j + 3][dp] = packh(a.w, b.w);
    }
    __syncthreads();
    int c = t >> 2;
    int rc = t & 3;
    uint4* dst = (uint4*)(out + (size_t)(cb + c) * R + rb + rc * 32);
    const unsigned* src = &sP[c][rc * 16];
#pragma unroll
    for (int j = 0; j < 4; j++)
        dst[j] = *(const uint4*)(src + j * 4);
}

// ---------------- Stage A: H = silu(x@Wg) * (x@Wu) ----------------
// 8-phase-style pipelined grouped GEMM. Tile: 256 tokens x 128 f-cols x {G,U}
// (= 256x256 effective). 8 waves (2M x 4N), BK=64 split in two 32-k slots.
// LDS ring: 2 buffers x 4 slots (A-lo, B-lo, A-hi, B-hi) x 16 KB = 128 KB.
// Per phase: stage ONE slot of k-tile t+1 (2 x gl2lds/thread), s_waitcnt vmcnt(6)
// (never 0 in steady state -> 3 slots always in flight), s_barrier, ds_read frags,
// setprio(1) around 16 MFMA, s_barrier. Tail drains 4 -> 2 -> 0.
// Slot readiness proof: slot staged at phase p is retired by the vmcnt(6) executed
// 4 phases later (8 outstanding -> 6), which is exactly its first use.
// Write safety: stages target buffer b^1 whose readers all finished at the previous
// k-tile's last barrier (full k-tile ping-pong).
#define STG_A(NB, SLOT, KO)                                                     \
    gl2lds16(srcA0 + (KO), &lds[(NB)*32768 + (SLOT)*8192 + tid*8]);             \
    gl2lds16(srcA1 + (KO), &lds[(NB)*32768 + (SLOT)*8192 + 4096 + tid*8])
#define STG_B(NB, SLOT, KO)                                                     \
    gl2lds16(srcB0 + (KO), &lds[(NB)*32768 + (SLOT)*8192 + tid*8]);             \
    gl2lds16(srcB1 + (KO), &lds[(NB)*32768 + (SLOT)*8192 + 4096 + tid*8])

#define PHASE(KS, NH, VM, STAGE_STMT)                                           \
    {                                                                           \
        STAGE_STMT;                                                             \
        vmw<VM>();                                                              \
        __builtin_amdgcn_s_barrier();                                           \
        if ((NH) == 0) {                                                        \
            _Pragma("unroll")                                                   \
            for (int mi = 0; mi < 8; mi++)                                      \
                a[mi] = *(const f16x8*)&lds[bofs + ((KS)?2:0)*8192 +            \
                         (wr*128 + mi*16 + fm)*32 + p8];                        \
        }                                                                       \
        bb0 = *(const f16x8*)&lds[bofs + ((KS)?3:1)*8192 +                      \
               (wc*64 + ((NH)*2+0)*16 + fm)*32 + p8];                           \
        bb1 = *(const f16x8*)&lds[bofs + ((KS)?3:1)*8192 +                      \
               (wc*64 + ((NH)*2+1)*16 + fm)*32 + p8];                           \
        __builtin_amdgcn_s_setprio(1);                                          \
        _Pragma("unroll")                                                       \
        for (int mi = 0; mi < 8; mi++) {                                        \
            acc[mi][(NH)*2+0] = __builtin_amdgcn_mfma_f32_16x16x32_f16(         \
                a[mi], bb0, acc[mi][(NH)*2+0], 0, 0, 0);                        \
            acc[mi][(NH)*2+1] = __builtin_amdgcn_mfma_f32_16x16x32_f16(         \
                a[mi], bb1, acc[mi][(NH)*2+1], 0, 0, 0);                        \
        }                                                                       \
        __builtin_amdgcn_s_setprio(0);                                          \
        __builtin_amdgcn_s_barrier();                                           \
    }

__global__ __launch_bounds__(512) void gateup_kernel(
    const f16_t* __restrict__ xf,
    const f16_t* __restrict__ wgT, const f16_t* __restrict__ wuT,
    const int* __restrict__ counts, const int* __restrict__ bucket,
    f16_t* __restrict__ H)
{
    // XCD-bijective remap: xcd = flat%8 owns one expert (256 blocks/expert),
    // within-expert m-fastest so resident blocks share ~2 n-panels (1 MB, L2-fit).
    int flat = blockIdx.x + (blockIdx.y << 4) + (blockIdx.z << 8);
    int chunk = ((flat & 7) << 8) | (flat >> 3);
    int e  = chunk >> 8;
    int rr = chunk & 255;
    int m0 = (rr & 15) * 256;
    int f0 = (rr >> 4) * 128;
    int cnt = counts[e * 32];
    if (m0 >= cnt) return;

    __shared__ f16_t lds[2 * 4 * 8192];   // 128 KB
    __shared__ int sEnt[256];

    int tid = threadIdx.x;
    if (tid < 256) {
        int i = m0 + tid;
        sEnt[tid] = bucket[e * N_TOK + (i < cnt ? i : m0)];
    }
    __syncthreads();

    int wave = tid >> 6, lane = tid & 63;
    int wr = wave >> 2, wc = wave & 3;      // 2M x 4N wave grid
    int fm = lane & 15, quad = lane >> 4;
    int p8 = ((quad + (fm >> 1)) & 3) * 8;  // rotation swizzle (measured 0-conflict)

    // staging sources: dest row = (j*512+tid)>>2, phys chunk = tid&3,
    // logical chunk c = (phys - (row>>1)) & 3
    int row0 = tid >> 2;
    int row1 = 128 + row0;
    int c0 = ((tid & 3) - (row0 >> 1)) & 3;
    int c1 = ((tid & 3) - (row1 >> 1)) & 3;
    const f16_t* srcA0 = xf + (size_t)(sEnt[row0] >> 1) * DIM + c0 * 8;
    const f16_t* srcA1 = xf + (size_t)(sEnt[row1] >> 1) * DIM + c1 * 8;
    // B rows: [wc4*64 .. +32) = Wg f-cols [f0+wc4*32..+32), [+32..+64) = Wu same
    int wc4_0 = row0 >> 6, sub0 = row0 & 63;
    int wc4_1 = row1 >> 6, sub1 = row1 & 63;
    const f16_t* srcB0 = ((sub0 & 32) ? wuT : wgT) +
        ((size_t)e * FDIM + f0 + wc4_0 * 32 + (sub0 & 31)) * DIM + c0 * 8;
    const f16_t* srcB1 = ((sub1 & 32) ? wuT : wgT) +
        ((size_t)e * FDIM + f0 + wc4_1 * 32 + (sub1 & 31)) * DIM + c1 * 8;

    f32x4 acc[8][4];                         // ni 0-1 = G, 2-3 = U (same f-cols)
    f32x4 zero = {0.f, 0.f, 0.f, 0.f};
#pragma unroll
    for (int i = 0; i < 8; i++)
#pragma unroll
        for (int j = 0; j < 4; j++) acc[i][j] = zero;

    f16x8 a[8], bb0, bb1;

    // prologue: fully stage k-tile 0 into buffer 0
    STG_A(0, 0, 0);
    STG_B(0, 1, 0);
    STG_A(0, 2, 32);
    STG_B(0, 3, 32);
    vmw<0>();
    __builtin_amdgcn_s_barrier();

    const int NT = DIM / 64;   // 16 k-tiles
    int b = 0;
    for (int t = 0; t < NT - 1; ++t) {
        int nb = b ^ 1;
        int bofs = b * 32768;
        int ko = (t + 1) * 64;
        PHASE(0, 0, 6, STG_A(nb, 0, ko));
        PHASE(0, 1, 6, STG_B(nb, 1, ko));
        PHASE(1, 0, 6, STG_A(nb, 2, ko + 32));
        PHASE(1, 1, 6, STG_B(nb, 3, ko + 32));
        b = nb;
    }
    {   // tail k-tile: drain 4 -> 4 -> 2 -> 0
        int bofs = b * 32768;
        PHASE(0, 0, 4, );
        PHASE(0, 1, 4, );
        PHASE(1, 0, 2, );
        PHASE(1, 1, 0, );
    }

    // epilogue: silu(G)*U -> H. C/D layout: col=lane&15, row=quad*4+i
    int crow = quad * 4;
#pragma unroll
    for (int mi = 0; mi < 8; mi++) {
#pragma unroll
        for (int i = 0; i < 4; i++) {
            int row = wr * 128 + mi * 16 + crow + i;
            if (m0 + row < cnt) {
                int ent = sEnt[row];
                f16_t* hr = H + (size_t)ent * FDIM + f0 + wc * 32;
#pragma unroll
                for (int ni = 0; ni < 2; ni++) {
                    float g = acc[mi][ni][i];
                    float u = acc[mi][ni + 2][i];
                    float h = (g / (1.f + __expf(-g))) * u;
                    hr[ni * 16 + fm] = (f16_t)h;
                }
            }
        }
    }
}

// ---------------- Stage B: Y[ent,d] = w[ent] * (H[ent,:] @ Wd); 128x128 ----------------
__global__ __launch_bounds__(256) void down_kernel(
    const f16_t* __restrict__ H, const f16_t* __restrict__ wdT,
    const int* __restrict__ counts, const int* __restrict__ bucket,
    const float* __restrict__ topw, float* __restrict__ Y)
{
    int e = blockIdx.z;
    int cnt = counts[e * 32];
    int m0 = blockIdx.y * 128;
    if (m0 >= cnt) return;
    int n0 = blockIdx.x * 128;

    __shared__ f16_t sA[128 * 32];
    __shared__ f16_t sB[128 * 32];
    __shared__ int sEnt[128];

    int tid = threadIdx.x;
    if (tid < 128) {
        int i = m0 + tid;
        sEnt[tid] = bucket[e * N_TOK + (i < cnt ? i : m0)];
    }
    __syncthreads();

    int wave = tid >> 6, lane = tid & 63;
    int q = ((lane & 3) - (lane >> 3)) & 3;
    int r0 = wave * 32 + (lane >> 2);
    int r1 = r0 + 16;
    const f16_t* gA0 = H + (size_t)sEnt[r0] * FDIM + q * 8;
    const f16_t* gA1 = H + (size_t)sEnt[r1] * FDIM + q * 8;
    const f16_t* gB0 = wdT + ((size_t)e * DIM + n0 + r0) * FDIM + q * 8;
    const f16_t* gB1 = wdT + ((size_t)e * DIM + n0 + r1) * FDIM + q * 8;
    f16_t* lA0 = &sA[wave * 1024 + lane * 8];
    f16_t* lA1 = lA0 + 512;
    f16_t* lB0 = &sB[wave * 1024 + lane * 8];
    f16_t* lB1 = lB0 + 512;

    f32x4 acc[4][4];
    f32x4 zero = {0.f, 0.f, 0.f, 0.f};
#pragma unroll
    for (int i = 0; i < 4; i++)
#pragma unroll
        for (int j = 0; j < 4; j++) acc[i][j] = zero;

    int wm = (wave & 1) * 64, wn = (wave >> 1) * 64;
    int fm = lane & 15, quad = lane >> 4;
    int p8 = ((quad + (fm >> 1)) & 3) * 8;

    for (int k0 = 0; k0 < FDIM; k0 += 32) {
        gl2lds16(gA0 + k0, lA0);
        gl2lds16(gA1 + k0, lA1);
        gl2lds16(gB0 + k0, lB0);
        gl2lds16(gB1 + k0, lB1);
        __syncthreads();
        f16x8 af[4], bf[4];
#pragma unroll
        for (int mi = 0; mi < 4; mi++)
            af[mi] = *(const f16x8*)&sA[(wm + mi * 16 + fm) * 32 + p8];
#pragma unroll
        for (int ni = 0; ni < 4; ni++)
            bf[ni] = *(const f16x8*)&sB[(wn + ni * 16 + fm) * 32 + p8];
#pragma unroll
        for (int mi = 0; mi < 4; mi++)
#pragma unroll
            for (int ni = 0; ni < 4; ni++)
                acc[mi][ni] = __builtin_amdgcn_mfma_f32_16x16x32_f16(af[mi], bf[ni], acc[mi][ni], 0, 0, 0);
        __syncthreads();
    }
    int crow = quad * 4, ccol = fm;
#pragma unroll
    for (int mi = 0; mi < 4; mi++) {
#pragma unroll
        for (int i = 0; i < 4; i++) {
            int m = wm + mi * 16 + crow + i;
            if (m0 + m < cnt) {
                int ent = sEnt[m];
                float w = topw[ent];
                float* yr = Y + (size_t)ent * DIM + n0 + wn;
#pragma unroll
                for (int ni = 0; ni < 4; ni++)
                    yr[ni * 16 + ccol] = w * acc[mi][ni][i];
            }
        }
    }
}

// ---------------- Combine: out[t] = Y[2t] + Y[2t+1] ----------------
__global__ __launch_bounds__(256) void combine_kernel(
    const float* __restrict__ Y, float* __restrict__ out)
{
    int i = blockIdx.x * 256 + threadIdx.x;
    int t = i >> 8;
    int c = i & 255;
    float4 a = ((const float4*)Y)[(size_t)(2 * t) * 256 + c];
    float4 b = ((const float4*)Y)[(size_t)(2 * t + 1) * 256 + c];
    float4 o;
    o.x = a.x + b.x; o.y = a.y + b.y; o.z = a.z + b.z; o.w = a.w + b.w;
    ((float4*)out)[i] = o;
}

extern "C" void kernel_launch(void* const* d_in, const int* in_sizes, int n_in,
                              void* d_out, int out_size, void* d_ws, size_t ws_size,
                              hipStream_t stream) {
    const float* x  = (const float*)d_in[0];
    const float* wr = (const float*)d_in[1];
    const float* wg = (const float*)d_in[2];
    const float* wu = (const float*)d_in[3];
    const float* wd = (const float*)d_in[4];
    float* out = (float*)d_out;
    char* ws = (char*)d_ws;
    const size_t MB = 1ull << 20;

    int*   counts = (int*)ws;                       // 1 KB
    int*   bucket = (int*)(ws + 1024);              // 128 KB
    float* topw   = (float*)(ws + 160 * 1024);      // 32 KB
    f16_t* xf     = (f16_t*)(ws + 1 * MB);          // 1..9 MB   (dead after gateup)
    f16_t* wgT    = (f16_t*)(ws + 9 * MB);          // 9..41 MB  (dead after gateup)
    f16_t* wuT    = (f16_t*)(ws + 41 * MB);         // 41..73 MB (dead after gateup)
    f16_t* H      = (f16_t*)(ws + 73 * MB);         // 73..105 MB
    f16_t* wdT    = (f16_t*)(ws + 1 * MB);          // alias 1..33 MB
    float* Y      = (float*)(ws + 33 * MB);         // alias 33..65 MB

    hipMemsetAsync(counts, 0, 1024, stream);
    router_kernel<<<256, 256, 0, stream>>>(x, wr, topw, counts, bucket);
    xcast_kernel<<<2048, 256, 0, stream>>>(x, xf);
    transpose_cvt<<<dim3(256, 16), 256, 0, stream>>>(wg, wu, wgT, wuT, DIM, FDIM, DIM / 128, NEXP);
    // pipelined 256x(128 f)x{G,U} grouped GEMM; grid decoded in-kernel (XCD remap)
    gateup_kernel<<<dim3(16, 16, 8), 512, 0, stream>>>(xf, wgT, wuT, counts, bucket, H);
    transpose_cvt<<<dim3(256, 8), 256, 0, stream>>>(wd, wd, wdT, wdT, FDIM, DIM, FDIM / 128, NEXP);
    down_kernel<<<dim3(DIM / 128, 32, NEXP), 256, 0, stream>>>(H, wdT, counts, bucket, topw, Y);
    combine_kernel<<<4096, 256, 0, stream>>>(Y, out);
}

// Round 2
// 432.915 us; speedup vs baseline: 1.0716x; 1.0716x over previous
//
#include <hip/hip_runtime.h>
#include <cstdint>

#define N_TOK 4096
#define DIM   1024
#define NEXP  8
#define FDIM  2048

typedef _Float16 f16_t;
typedef _Float16 f16x8 __attribute__((ext_vector_type(8)));
typedef float    f32x4 __attribute__((ext_vector_type(4)));

__device__ inline unsigned packh(float a, float b) {
    union { f16_t h[2]; unsigned u; } p;
    p.h[0] = (f16_t)a; p.h[1] = (f16_t)b;
    return p.u;
}

// async global->LDS, 16B per lane; LDS dest must be base + lane*16 (it is, by construction)
__device__ inline void gl2lds16(const void* g, void* l) {
    __builtin_amdgcn_global_load_lds(
        (const __attribute__((address_space(1))) unsigned*)g,
        (__attribute__((address_space(3))) unsigned*)l, 16, 0, 0);
}

template<int N>
__device__ inline void vmw() {
    asm volatile("s_waitcnt vmcnt(%0)" :: "i"(N) : "memory");
}

// ---------------- Router: fp32 logits -> softmax -> top2 -> two-level scatter ----------------
__global__ __launch_bounds__(256) void router_kernel(
    const float* __restrict__ x, const float* __restrict__ wr,
    float* __restrict__ topw, int* __restrict__ counts, int* __restrict__ bucket)
{
    __shared__ float r[NEXP][DIM];   // router transposed, 32 KB
    __shared__ int sIdx[32];         // per-block top2 expert ids, 2 per token
    int tid = threadIdx.x;
    for (int i = tid; i < DIM * NEXP / 4; i += 256) {
        float4 v = ((const float4*)wr)[i];
        int base = i * 4;                    // flat = d*8 + e
        r[(base + 0) & 7][(base + 0) >> 3] = v.x;
        r[(base + 1) & 7][(base + 1) >> 3] = v.y;
        r[(base + 2) & 7][(base + 2) >> 3] = v.z;
        r[(base + 3) & 7][(base + 3) >> 3] = v.w;
    }
    __syncthreads();
    int wave = tid >> 6, lane = tid & 63;
    int t0 = blockIdx.x * 16 + wave * 4;
    for (int tt = 0; tt < 4; ++tt) {
        int t = t0 + tt;
        float acc[NEXP];
#pragma unroll
        for (int e = 0; e < NEXP; e++) acc[e] = 0.f;
        const float* xr = x + (size_t)t * DIM;
#pragma unroll
        for (int k = 0; k < DIM / 64; k++) {
            int d = lane + k * 64;
            float xv = xr[d];
#pragma unroll
            for (int e = 0; e < NEXP; e++) acc[e] += xv * r[e][d];
        }
#pragma unroll
        for (int e = 0; e < NEXP; e++) {
#pragma unroll
            for (int off = 32; off > 0; off >>= 1)
                acc[e] += __shfl_xor(acc[e], off, 64);
        }
        if (lane == 0) {
            float mx = acc[0];
#pragma unroll
            for (int e = 1; e < NEXP; e++) mx = fmaxf(mx, acc[e]);
            float p[NEXP]; float s = 0.f;
#pragma unroll
            for (int e = 0; e < NEXP; e++) { p[e] = expf(acc[e] - mx); s += p[e]; }
            float inv = 1.f / s;
#pragma unroll
            for (int e = 0; e < NEXP; e++) p[e] *= inv;
            int i1 = 0; float p1 = p[0];
#pragma unroll
            for (int e = 1; e < NEXP; e++) if (p[e] > p1) { p1 = p[e]; i1 = e; }
            int i2 = -1; float p2 = -1.f;
#pragma unroll
            for (int e = 0; e < NEXP; e++) if (e != i1 && p[e] > p2) { p2 = p[e]; i2 = e; }
            float e2 = expf(p2 - p1);          // softmax over top-2 probs
            float w1 = 1.f / (1.f + e2);
            topw[t * 2 + 0] = w1;
            topw[t * 2 + 1] = e2 * w1;
            int j = (wave * 4 + tt) * 2;
            sIdx[j + 0] = i1;
            sIdx[j + 1] = i2;
        }
    }
    __syncthreads();
    if (tid < NEXP) {
        int cnt = 0;
#pragma unroll
        for (int j = 0; j < 32; j++) cnt += (sIdx[j] == tid) ? 1 : 0;
        if (cnt > 0) {
            int pos = atomicAdd(&counts[tid * 32], cnt);
#pragma unroll
            for (int j = 0; j < 32; j++)
                if (sIdx[j] == tid)
                    bucket[tid * N_TOK + pos++] = (blockIdx.x * 16 + (j >> 1)) * 2 + (j & 1);
        }
    }
}

// ---------------- x: fp32 -> f16 ----------------
__global__ __launch_bounds__(256) void xcast_kernel(const float* __restrict__ x, f16_t* __restrict__ xf)
{
    int i = blockIdx.x * 256 + threadIdx.x;   // 8 elements per thread
    float4 a = ((const float4*)x)[2 * i];
    float4 b = ((const float4*)x)[2 * i + 1];
    union { f16_t h[8]; uint4 u; } p;
    p.h[0] = (f16_t)a.x; p.h[1] = (f16_t)a.y; p.h[2] = (f16_t)a.z; p.h[3] = (f16_t)a.w;
    p.h[4] = (f16_t)b.x; p.h[5] = (f16_t)b.y; p.h[6] = (f16_t)b.z; p.h[7] = (f16_t)b.w;
    ((uint4*)xf)[i] = p.u;
}

// ---------------- Weight transpose+convert: in [R][C] fp32 -> out [C][R] f16 ----------------
__global__ __launch_bounds__(256) void transpose_cvt(
    const float* __restrict__ inA, const float* __restrict__ inB,
    f16_t* __restrict__ outA, f16_t* __restrict__ outB,
    int R, int C, int tiles_r, int nA)
{
    __shared__ unsigned sP[64][68];
    int m = blockIdx.y;
    const float* in; f16_t* out;
    if (m < nA) { in = inA + (size_t)m * DIM * FDIM; out = outA + (size_t)m * DIM * FDIM; }
    else        { in = inB + (size_t)(m - nA) * DIM * FDIM; out = outB + (size_t)(m - nA) * DIM * FDIM; }
    int tix = blockIdx.x;
    int rb = (tix % tiles_r) * 128;
    int cb = (tix / tiles_r) * 64;
    int t = threadIdx.x;
    int dp = t >> 2;
    int fc = (t & 3) * 16;
    const float* r0 = in + (size_t)(rb + 2 * dp) * C + cb + fc;
    const float* r1 = r0 + C;
#pragma unroll
    for (int j = 0; j < 16; j += 4) {
        float4 a = *(const float4*)(r0 + j);
        float4 b = *(const float4*)(r1 + j);
        sP[fc + j + 0][dp] = packh(a.x, b.x);
        sP[fc + j + 1][dp] = packh(a.y, b.y);
        sP[fc + j + 2][dp] = packh(a.z, b.z);
        sP[fc + j + 3][dp] = packh(a.w, b.w);
    }
    __syncthreads();
    int c = t >> 2;
    int rc = t & 3;
    uint4* dst = (uint4*)(out + (size_t)(cb + c) * R + rb + rc * 32);
    const unsigned* src = &sP[c][rc * 16];
#pragma unroll
    for (int j = 0; j < 4; j++)
        dst[j] = *(const uint4*)(src + j * 4);
}

// ---------------- Stage A: H = silu(x@Wg) * (x@Wu) ----------------
// Pipelined grouped GEMM, m201/AITER-style schedule.
// Tile: 256 tokens x 128 f x {G,U} (effective 256x256), 8 waves (2M x 4N).
// BK=32 k-tiles; LDS ring of 4 buffers x (A 16KB + B 16KB) = 128 KB.
// Staging runs 3 k-tiles ahead: k-tile t's phases stage A/B of k-tile t+3.
// Phase = { ds_read this phase's frags (safe: slot vmcnt-retired a phase ago
//           + barrier), stage one 16KB slot (2 gl2lds/thread), vmcnt(8)
//           counted wait (6-phase prefetch depth, never 0 in main loop),
//           s_barrier, setprio(1), 16 MFMA, setprio(0) }.
// One barrier per 16 MFMA; LDS-read latency hides under the barrier wait.
// WAR safety on re-stage: slot re-staged at phase g was last read at g-2; the
// MFMA consuming that read drains it before barrier g-1, which precedes the
// staging issue in every wave's program order.
// Tail: vmcnt drains 8 -> 4 -> 0 over the last 3 k-tiles.
#define STG_A(BOFS, KO)                                                         \
    gl2lds16(srcA0 + (KO), &lds[(BOFS) + tid * 8]);                             \
    gl2lds16(srcA1 + (KO), &lds[(BOFS) + 4096 + tid * 8])
#define STG_B(BOFS, KO)                                                         \
    gl2lds16(srcB0 + (KO), &lds[(BOFS) + 8192 + tid * 8]);                      \
    gl2lds16(srcB1 + (KO), &lds[(BOFS) + 8192 + 4096 + tid * 8])

#define PHASE(RB, NH, VM, STAGE_STMT)                                           \
    {                                                                           \
        if ((NH) == 0) {                                                        \
            _Pragma("unroll")                                                   \
            for (int mi = 0; mi < 8; mi++)                                      \
                a[mi] = *(const f16x8*)&lds[(RB) +                              \
                         (wr * 128 + mi * 16 + fm) * 32 + p8];                  \
        }                                                                       \
        bb0 = *(const f16x8*)&lds[(RB) + 8192 +                                 \
               (wc * 64 + ((NH) * 2 + 0) * 16 + fm) * 32 + p8];                 \
        bb1 = *(const f16x8*)&lds[(RB) + 8192 +                                 \
               (wc * 64 + ((NH) * 2 + 1) * 16 + fm) * 32 + p8];                 \
        STAGE_STMT;                                                             \
        vmw<VM>();                                                              \
        __builtin_amdgcn_s_barrier();                                           \
        __builtin_amdgcn_s_setprio(1);                                          \
        _Pragma("unroll")                                                       \
        for (int mi = 0; mi < 8; mi++) {                                        \
            acc[mi][(NH) * 2 + 0] = __builtin_amdgcn_mfma_f32_16x16x32_f16(     \
                a[mi], bb0, acc[mi][(NH) * 2 + 0], 0, 0, 0);                    \
            acc[mi][(NH) * 2 + 1] = __builtin_amdgcn_mfma_f32_16x16x32_f16(     \
                a[mi], bb1, acc[mi][(NH) * 2 + 1], 0, 0, 0);                    \
        }                                                                       \
        __builtin_amdgcn_s_setprio(0);                                          \
    }

__global__ __launch_bounds__(512) void gateup_kernel(
    const f16_t* __restrict__ xf,
    const f16_t* __restrict__ wgT, const f16_t* __restrict__ wuT,
    const int* __restrict__ counts, const int* __restrict__ bucket,
    f16_t* __restrict__ H)
{
    // XCD-bijective remap: xcd = flat%8 owns one expert (256 blocks/expert),
    // within-expert m-fastest so resident blocks share ~2 n-panels (L2-fit).
    int flat = blockIdx.x + (blockIdx.y << 4) + (blockIdx.z << 8);
    int chunk = ((flat & 7) << 8) | (flat >> 3);
    int e  = chunk >> 8;
    int rr = chunk & 255;
    int m0 = (rr & 15) * 256;
    int f0 = (rr >> 4) * 128;
    int cnt = counts[e * 32];
    if (m0 >= cnt) return;

    __shared__ f16_t lds[4 * 16384];   // 128 KB: 4-deep ring of (A 8192 | B 8192) f16
    __shared__ int sEnt[256];

    int tid = threadIdx.x;
    if (tid < 256) {
        int i = m0 + tid;
        sEnt[tid] = bucket[e * N_TOK + (i < cnt ? i : m0)];
    }
    __syncthreads();

    int wave = tid >> 6, lane = tid & 63;
    int wr = wave >> 2, wc = wave & 3;      // 2M x 4N wave grid
    int fm = lane & 15, quad = lane >> 4;
    int p8 = ((quad + (fm >> 1)) & 3) * 8;  // rotation swizzle (measured 0-conflict)

    // staging sources: dest row = (j*512+tid)>>2, phys chunk = tid&3,
    // logical chunk c = (phys - (row>>1)) & 3
    int row0 = tid >> 2;
    int row1 = 128 + row0;
    int c0 = ((tid & 3) - (row0 >> 1)) & 3;
    int c1 = ((tid & 3) - (row1 >> 1)) & 3;
    const f16_t* srcA0 = xf + (size_t)(sEnt[row0] >> 1) * DIM + c0 * 8;
    const f16_t* srcA1 = xf + (size_t)(sEnt[row1] >> 1) * DIM + c1 * 8;
    // B rows: per wc-panel of 32 f: rows [wc*64..+32) = Wg, [+32..+64) = Wu
    int wc4_0 = row0 >> 6, sub0 = row0 & 63;
    int wc4_1 = row1 >> 6, sub1 = row1 & 63;
    const f16_t* srcB0 = ((sub0 & 32) ? wuT : wgT) +
        ((size_t)e * FDIM + f0 + wc4_0 * 32 + (sub0 & 31)) * DIM + c0 * 8;
    const f16_t* srcB1 = ((sub1 & 32) ? wuT : wgT) +
        ((size_t)e * FDIM + f0 + wc4_1 * 32 + (sub1 & 31)) * DIM + c1 * 8;

    f32x4 acc[8][4];                         // ni 0-1 = G, 2-3 = U (same f-cols)
    f32x4 zero = {0.f, 0.f, 0.f, 0.f};
#pragma unroll
    for (int i = 0; i < 8; i++)
#pragma unroll
        for (int j = 0; j < 4; j++) acc[i][j] = zero;

    f16x8 a[8], bb0, bb1;

    // prologue: fully stage k-tiles 0,1,2 into buffers 0,1,2 (6 slot-pairs)
    STG_A(0, 0);      STG_B(0, 0);
    STG_A(16384, 32); STG_B(16384, 32);
    STG_A(32768, 64); STG_B(32768, 64);
    vmw<8>();
    __builtin_amdgcn_s_barrier();

    const int NT = DIM / 32;   // 32 k-tiles
    int rb = 0;                // read-buffer offset (f16 units)
    for (int t = 0; t < NT - 3; ++t) {
        int sb = (rb + 49152) & 65535;      // stage buffer = read buffer - 1 (mod 4)
        int ko = (t + 3) * 32;
        PHASE(rb, 0, 8, STG_A(sb, ko));
        PHASE(rb, 1, 8, STG_B(sb, ko));
        rb = (rb + 16384) & 65535;
    }
    // tail: k-tile NT-3
    PHASE(rb, 0, 8, );
    PHASE(rb, 1, 4, );
    rb = (rb + 16384) & 65535;
    // k-tile NT-2
    PHASE(rb, 0, 4, );
    PHASE(rb, 1, 0, );
    rb = (rb + 16384) & 65535;
    // k-tile NT-1
    PHASE(rb, 0, 0, );
    PHASE(rb, 1, 0, );

    // epilogue: silu(G)*U -> H. C/D layout: col=lane&15, row=quad*4+i
    int crow = quad * 4;
#pragma unroll
    for (int mi = 0; mi < 8; mi++) {
#pragma unroll
        for (int i = 0; i < 4; i++) {
            int row = wr * 128 + mi * 16 + crow + i;
            if (m0 + row < cnt) {
                int ent = sEnt[row];
                f16_t* hr = H + (size_t)ent * FDIM + f0 + wc * 32;
#pragma unroll
                for (int ni = 0; ni < 2; ni++) {
                    float g = acc[mi][ni][i];
                    float u = acc[mi][ni + 2][i];
                    float h = (g / (1.f + __expf(-g))) * u;
                    hr[ni * 16 + fm] = (f16_t)h;
                }
            }
        }
    }
}

// ---------------- Stage B: Y[ent,d] = w[ent] * (H[ent,:] @ Wd); 128x128 ----------------
__global__ __launch_bounds__(256) void down_kernel(
    const f16_t* __restrict__ H, const f16_t* __restrict__ wdT,
    const int* __restrict__ counts, const int* __restrict__ bucket,
    const float* __restrict__ topw, float* __restrict__ Y)
{
    int e = blockIdx.z;
    int cnt = counts[e * 32];
    int m0 = blockIdx.y * 128;
    if (m0 >= cnt) return;
    int n0 = blockIdx.x * 128;

    __shared__ f16_t sA[128 * 32];
    __shared__ f16_t sB[128 * 32];
    __shared__ int sEnt[128];

    int tid = threadIdx.x;
    if (tid < 128) {
        int i = m0 + tid;
        sEnt[tid] = bucket[e * N_TOK + (i < cnt ? i : m0)];
    }
    __syncthreads();

    int wave = tid >> 6, lane = tid & 63;
    int q = ((lane & 3) - (lane >> 3)) & 3;
    int r0 = wave * 32 + (lane >> 2);
    int r1 = r0 + 16;
    const f16_t* gA0 = H + (size_t)sEnt[r0] * FDIM + q * 8;
    const f16_t* gA1 = H + (size_t)sEnt[r1] * FDIM + q * 8;
    const f16_t* gB0 = wdT + ((size_t)e * DIM + n0 + r0) * FDIM + q * 8;
    const f16_t* gB1 = wdT + ((size_t)e * DIM + n0 + r1) * FDIM + q * 8;
    f16_t* lA0 = &sA[wave * 1024 + lane * 8];
    f16_t* lA1 = lA0 + 512;
    f16_t* lB0 = &sB[wave * 1024 + lane * 8];
    f16_t* lB1 = lB0 + 512;

    f32x4 acc[4][4];
    f32x4 zero = {0.f, 0.f, 0.f, 0.f};
#pragma unroll
    for (int i = 0; i < 4; i++)
#pragma unroll
        for (int j = 0; j < 4; j++) acc[i][j] = zero;

    int wm = (wave & 1) * 64, wn = (wave >> 1) * 64;
    int fm = lane & 15, quad = lane >> 4;
    int p8 = ((quad + (fm >> 1)) & 3) * 8;

    for (int k0 = 0; k0 < FDIM; k0 += 32) {
        gl2lds16(gA0 + k0, lA0);
        gl2lds16(gA1 + k0, lA1);
        gl2lds16(gB0 + k0, lB0);
        gl2lds16(gB1 + k0, lB1);
        __syncthreads();
        f16x8 af[4], bf[4];
#pragma unroll
        for (int mi = 0; mi < 4; mi++)
            af[mi] = *(const f16x8*)&sA[(wm + mi * 16 + fm) * 32 + p8];
#pragma unroll
        for (int ni = 0; ni < 4; ni++)
            bf[ni] = *(const f16x8*)&sB[(wn + ni * 16 + fm) * 32 + p8];
#pragma unroll
        for (int mi = 0; mi < 4; mi++)
#pragma unroll
            for (int ni = 0; ni < 4; ni++)
                acc[mi][ni] = __builtin_amdgcn_mfma_f32_16x16x32_f16(af[mi], bf[ni], acc[mi][ni], 0, 0, 0);
        __syncthreads();
    }
    int crow = quad * 4, ccol = fm;
#pragma unroll
    for (int mi = 0; mi < 4; mi++) {
#pragma unroll
        for (int i = 0; i < 4; i++) {
            int m = wm + mi * 16 + crow + i;
            if (m0 + m < cnt) {
                int ent = sEnt[m];
                float w = topw[ent];
                float* yr = Y + (size_t)ent * DIM + n0 + wn;
#pragma unroll
                for (int ni = 0; ni < 4; ni++)
                    yr[ni * 16 + ccol] = w * acc[mi][ni][i];
            }
        }
    }
}

// ---------------- Combine: out[t] = Y[2t] + Y[2t+1] ----------------
__global__ __launch_bounds__(256) void combine_kernel(
    const float* __restrict__ Y, float* __restrict__ out)
{
    int i = blockIdx.x * 256 + threadIdx.x;
    int t = i >> 8;
    int c = i & 255;
    float4 a = ((const float4*)Y)[(size_t)(2 * t) * 256 + c];
    float4 b = ((const float4*)Y)[(size_t)(2 * t + 1) * 256 + c];
    float4 o;
    o.x = a.x + b.x; o.y = a.y + b.y; o.z = a.z + b.z; o.w = a.w + b.w;
    ((float4*)out)[i] = o;
}

extern "C" void kernel_launch(void* const* d_in, const int* in_sizes, int n_in,
                              void* d_out, int out_size, void* d_ws, size_t ws_size,
                              hipStream_t stream) {
    const float* x  = (const float*)d_in[0];
    const float* wr = (const float*)d_in[1];
    const float* wg = (const float*)d_in[2];
    const float* wu = (const float*)d_in[3];
    const float* wd = (const float*)d_in[4];
    float* out = (float*)d_out;
    char* ws = (char*)d_ws;
    const size_t MB = 1ull << 20;

    int*   counts = (int*)ws;                       // 1 KB
    int*   bucket = (int*)(ws + 1024);              // 128 KB
    float* topw   = (float*)(ws + 160 * 1024);      // 32 KB
    f16_t* xf     = (f16_t*)(ws + 1 * MB);          // 1..9 MB   (dead after gateup)
    f16_t* wgT    = (f16_t*)(ws + 9 * MB);          // 9..41 MB  (dead after gateup)
    f16_t* wuT    = (f16_t*)(ws + 41 * MB);         // 41..73 MB (dead after gateup)
    f16_t* H      = (f16_t*)(ws + 73 * MB);         // 73..105 MB
    f16_t* wdT    = (f16_t*)(ws + 1 * MB);          // alias 1..33 MB
    float* Y      = (float*)(ws + 33 * MB);         // alias 33..65 MB

    hipMemsetAsync(counts, 0, 1024, stream);
    router_kernel<<<256, 256, 0, stream>>>(x, wr, topw, counts, bucket);
    xcast_kernel<<<2048, 256, 0, stream>>>(x, xf);
    transpose_cvt<<<dim3(256, 16), 256, 0, stream>>>(wg, wu, wgT, wuT, DIM, FDIM, DIM / 128, NEXP);
    gateup_kernel<<<dim3(16, 16, 8), 512, 0, stream>>>(xf, wgT, wuT, counts, bucket, H);
    transpose_cvt<<<dim3(256, 8), 256, 0, stream>>>(wd, wd, wdT, wdT, FDIM, DIM, FDIM / 128, NEXP);
    down_kernel<<<dim3(DIM / 128, 32, NEXP), 256, 0, stream>>>(H, wdT, counts, bucket, topw, Y);
    combine_kernel<<<4096, 256, 0, stream>>>(Y, out);
}